// Round 9
// baseline (129.148 us; speedup 1.0000x reference)
//
#include <hip/hip_runtime.h>
#include <math.h>

#define CIN    64
#define OUTC   64
#define BOT    16
#define KK     9
#define HH     48
#define WW     48
#define LPIX   (HH*WW)
#define WSZ    9216
#define PSZ    1024
#define PREDCH 10304
#define GRPSZ  2576
#define BATCH  2
#define NPX    18          // 3 rows x 6 cols of pixels per block
#define PXS2   1172        // px-stride (ushorts): 64*18 + 20 pad (conflict-free)
#define QS2    1160        // Q px-stride (ushorts): 64*18 + 8 pad
#define DBS    65

typedef __attribute__((ext_vector_type(8))) short short8v;
typedef __attribute__((ext_vector_type(4))) float float4v;

__device__ inline unsigned short f2bf(float f){
    unsigned u = __float_as_uint(f);
    return (unsigned short)((u + 0x7FFFu + ((u>>16)&1u)) >> 16);   // RNE
}

__global__ __launch_bounds__(256) void cvt_wp(const float* __restrict__ Wp,
                                              unsigned short* __restrict__ Wb) {
    const int n = PREDCH * 16;
    for (int i = blockIdx.x * 256 + threadIdx.x; i < n; i += gridDim.x * 256)
        Wb[i] = f2bf(Wp[i]);
}

// Block = 18 px (3x6), grid 256 (1/CU), 1024 threads (16 waves).
// vs dppc15 (R8, 74.8us, VALU-issue/barrier-bound):
//  (a) counter-balanced PRED split: waves 0-7 carry 5 Y-tasks, so they now
//      get only 3 PRED u-iters; waves 8-15 (4 Y-tasks) get 5 (8x3+8x5=64).
//      Per-tap per-wave load equalizes (3P+5Y vs 5P+4Y); the per-tap
//      barrier previously idled half the block behind the 4P+5Y waves
//      (~11% critical-path tax).
//  (b) dpacc * rsqrtf(max(nacc,1e-24)) replaces div+sqrt (~20 VALU -> ~8);
//      exact at the clamp boundary vs ref's /max(sqrt(n),1e-12).
// R6 bisect closed: cvt_pk inline-asm was the NaN culprit (remap + packed
// b32 stores verified correct in R8).  No inline asm used.
__global__ __launch_bounds__(1024) __attribute__((amdgpu_waves_per_eu(4, 4)))
void dppc16(
    const float* __restrict__ x,
    const unsigned short* __restrict__ Wb,
    const float* __restrict__ bp,
    float* __restrict__ out)
{
    __shared__ float          xt[64 * 5 * 8];       // 10240 B  [c][r5][c8]
    __shared__ float          xtT[5 * 8 * 64];      // 10240 B  [r5*8+c8][c]
    __shared__ unsigned short S[2][NPX * PXS2];     // 84384 B  P_t dbuf
    __shared__ unsigned short Qs[NPX * QS2];        // 41760 B  Q [px][o*18+d]
    __shared__ unsigned short Bfs[4 * 2 * 64 * 8];  //  8192 B  pred B-frags [g][nt][lane]
    __shared__ float          dynb[NPX * DBS];      //  4680 B

    const int tid  = threadIdx.x;
    const int wave = tid >> 6;
    const int lane = tid & 63;
    const int quad = lane >> 4;
    const int lrow = lane & 15;

    const int bi = blockIdx.x;
    const int b  = bi >> 7;
    const int r  = bi & 127;
    const int h0 = (r >> 3) * 3;
    const int w0 = (r & 7) * 6;

    // ---- xt load (coalesced global) ----
    const float* xb = x + (size_t)b * CIN * LPIX;
    for (int i = tid; i < 64 * 5 * 8; i += 1024) {
        const int c  = i / 40;
        const int rm = i - c * 40;
        const int hi = h0 - 1 + (rm >> 3);
        const int wi = w0 - 1 + (rm & 7);
        float v = 0.0f;
        if (hi >= 0 && hi < HH && wi >= 0 && wi < WW)
            v = xb[c * LPIX + hi * WW + wi];
        xt[i] = v;
    }
    __syncthreads();

    // ---- waves 0-7: pred B-frags -> LDS (wave-invariant, built once) ----
    if (wave < 8) {
        const int g  = wave >> 1;
        const int nt = wave & 1;
        const int px = nt * 16 + lrow;
        short8v f = (short8v)0;
        if (quad < 2 && px < NPX) {
            const int pr = px / 6, pc = px - 6 * (px / 6);
            #pragma unroll
            for (int j = 0; j < 8; ++j)
                f[j] = (short)f2bf(xt[((g * 16 + quad * 8 + j) * 5 + pr + 1) * 8 + pc + 1]);
        }
        if (quad == 2 && px < NPX) f[0] = (short)0x3F80;   // bf16(1.0) bias slot
        *(short8v*)&Bfs[((g * 2 + nt) * 64 + lane) * 8] = f;
    } else {
        // ---- waves 8-15: transpose xt -> xtT[spatial][c] (for pv b128 reads) ----
        for (int i = tid - 512; i < 64 * 5 * 8; i += 512) {
            const int sp = i >> 6;
            const int c  = i & 63;
            xtT[i] = xt[c * 40 + sp];
        }
    }
    __syncthreads();

    // ---- Q + dyn_b phase (group 3), Q -> Qs as [px][o*18+d] ----
    for (int u = wave; u < 68; u += 16) {
        const int ch0  = WSZ + u * 16;
        const int mych = ch0 + lrow;
        short8v a = (short8v)0;
        if (quad < 2)       a = *(const short8v*)(Wb + (size_t)mych * 16 + quad * 8);
        else if (quad == 2) a[0] = (short)f2bf(bp[mych]);
        #pragma unroll
        for (int nt = 0; nt < 2; ++nt) {
            const short8v bfr = *(const short8v*)&Bfs[((3 * 2 + nt) * 64 + lane) * 8];
            float4v Dv = {0.f, 0.f, 0.f, 0.f};
            Dv = __builtin_amdgcn_mfma_f32_16x16x32_bf16(a, bfr, Dv, 0, 0, 0);
            const int px = nt * 16 + lrow;
            if (px < NPX) {
                if (u < 64) {   // proj region: 4 consecutive ushorts, C-packed b32
                    const unsigned r01 = (unsigned)f2bf(Dv[0]) | ((unsigned)f2bf(Dv[1]) << 16);
                    const unsigned r23 = (unsigned)f2bf(Dv[2]) | ((unsigned)f2bf(Dv[3]) << 16);
                    unsigned short* p = &Qs[px * QS2 + u * 18 + quad * 4];
                    *(unsigned int*)(p)     = r01;
                    *(unsigned int*)(p + 2) = r23;
                } else {        // dyn_b region
                    #pragma unroll
                    for (int rr = 0; rr < 4; ++rr)
                        dynb[px * DBS + (u - 64) * 16 + quad * 4 + rr] = Dv[rr];
                }
            }
        }
    }

    // ---- PRED work split, counter-balanced against Y tasks ----
    // waves 0-7: 3 u-iters (they carry 5 Y-tasks); waves 8-15: 5 u-iters.
    const int pbase = (wave < 8) ? wave * 3 : 24 + (wave - 8) * 5;
    const int pcnt  = (wave < 8) ? 3 : 5;

    // ---- pred slice for tap t into buf ----
    // Row remap: A-row lrow -> channel chmin + (lrow&3)*576 + (lrow>>2)*9,
    // so Dv[rr] = (d=d0+rr, c=c0+quad): d-consecutive -> C-packed b32 stores.
    #define PASS(GG, NT)                                                              \
        { short8v am = (myg == (GG)) ? a : (short8v)0;                                \
          const short8v bfr = *(const short8v*)&Bfs[(((GG) * 2 + (NT)) * 64 + lane) * 8]; \
          Dv = __builtin_amdgcn_mfma_f32_16x16x32_bf16(am, bfr, Dv, 0, 0, 0); }

    #define PRED_SLICE(T, BUF)                                                        \
    for (int uu = 0; uu < pcnt; ++uu) {                                               \
        const int u  = pbase + uu;                                                    \
        const int d0 = (u >> 4) * 4;                                                  \
        const int c0 = (u & 15) * 4;                                                  \
        const int chmin = d0 * 576 + c0 * 9 + (T);                                    \
        const int mych  = chmin + (lrow & 3) * 576 + (lrow >> 2) * 9;                 \
        short8v a = (short8v)0;                                                       \
        if (quad < 2)       a = *(const short8v*)(Wb + (size_t)mych * 16 + quad * 8); \
        else if (quad == 2) a[0] = (short)f2bf(bp[mych]);                             \
        const int g0  = chmin / GRPSZ;                                                \
        const int g1  = (chmin + 1755) / GRPSZ;                                       \
        const int myg = mych / GRPSZ;                                                 \
        _Pragma("unroll")                                                             \
        for (int nt = 0; nt < 2; ++nt) {                                              \
            float4v Dv = {0.f, 0.f, 0.f, 0.f};                                        \
            if (g0 == 0)      { PASS(0, nt) if (g1 == 1) PASS(1, nt) }                \
            else if (g0 == 1) { PASS(1, nt) if (g1 == 2) PASS(2, nt) }                \
            else if (g0 == 2) { PASS(2, nt) if (g1 == 3) PASS(3, nt) }                \
            else              { PASS(3, nt) }                                         \
            const int px = nt * 16 + lrow;                                            \
            if (px < NPX) {                                                           \
                const unsigned r01 = (unsigned)f2bf(Dv[0]) | ((unsigned)f2bf(Dv[1]) << 16); \
                const unsigned r23 = (unsigned)f2bf(Dv[2]) | ((unsigned)f2bf(Dv[3]) << 16); \
                unsigned short* p = &S[BUF][px * PXS2 + (c0 + quad) * 18 + d0];       \
                *(unsigned int*)(p)     = r01;                                        \
                *(unsigned int*)(p + 2) = r23;                                        \
            }                                                                         \
        }                                                                             \
    }

    PRED_SLICE(0, 0)
    __syncthreads();   // covers Qs, dynb, S[0]

    // ---- Y-task assignment: 72 (px,Nt) tasks over 16 waves ----
    const int ntask  = (wave < 8) ? 5 : 4;
    const int tstart = (wave < 8) ? 5 * wave : 40 + 4 * (wave - 8);
    float acc[5] = {0.f, 0.f, 0.f, 0.f, 0.f};

    for (int t = 0; t < KK; ++t) {
        const int buf = t & 1;
        if (t < 8) { PRED_SLICE(t + 1, (t + 1) & 1) }

        const int tr = t / 3, tc = t - 3 * (t / 3);

        int lastpx = -1;
        short8v Ap[4];
        float4v pv4[4];
        #pragma unroll
        for (int k = 0; k < 5; ++k) {
            if (k < ntask) {
                const int tau = tstart + k;
                const int px  = tau >> 2;
                const int Nt  = tau & 3;
                const int pr = px / 6, pc = px - 6 * (px / 6);

                if (px != lastpx) {          // wave-uniform branch
                    lastpx = px;
                    #pragma unroll
                    for (int Mt = 0; Mt < 4; ++Mt) {
                        short8v f = (short8v)0;
                        if (quad < 2)
                            f = *(const short8v*)&S[buf][px * PXS2 + (Mt * 16 + lrow) * 18 + quad * 8];
                        Ap[Mt] = f;
                    }
                    const int spb = ((pr + tr) * 8 + pc + tc) * 64;
                    #pragma unroll
                    for (int Mt = 0; Mt < 4; ++Mt)
                        pv4[Mt] = *(const float4v*)&xtT[spb + Mt * 16 + quad * 4];
                }

                short8v Bqf = (short8v)0;
                if (quad < 2)
                    Bqf = *(const short8v*)&Qs[px * QS2 + (Nt * 16 + lrow) * 18 + quad * 8];

                float nacc = 0.f, dpacc = 0.f;
                #pragma unroll
                for (int Mt = 0; Mt < 4; ++Mt) {
                    float4v Dv = {0.f, 0.f, 0.f, 0.f};
                    Dv = __builtin_amdgcn_mfma_f32_16x16x32_bf16(Ap[Mt], Bqf, Dv, 0, 0, 0);
                    #pragma unroll
                    for (int rr = 0; rr < 4; ++rr) {
                        nacc  += Dv[rr] * Dv[rr];
                        dpacc += pv4[Mt][rr] * Dv[rr];
                    }
                }
                nacc  += __shfl_xor(nacc, 16);  nacc  += __shfl_xor(nacc, 32);
                dpacc += __shfl_xor(dpacc, 16); dpacc += __shfl_xor(dpacc, 32);
                acc[k] += dpacc * rsqrtf(fmaxf(nacc, 1e-24f));
            }
        }
        __syncthreads();
    }

    // ---- write out ----
    if (quad == 0) {
        #pragma unroll
        for (int k = 0; k < 5; ++k) {
            if (k < ntask) {
                const int tau = tstart + k;
                const int px  = tau >> 2;
                const int Nt  = tau & 3;
                const int pr = px / 6, pc = px - 6 * (px / 6);
                const int l  = (h0 + pr) * WW + (w0 + pc);
                const int o  = Nt * 16 + lrow;
                out[((size_t)b * OUTC + o) * LPIX + l] = acc[k] + dynb[px * DBS + o];
            }
        }
    }
}

extern "C" void kernel_launch(void* const* d_in, const int* in_sizes, int n_in,
                              void* d_out, int out_size, void* d_ws, size_t ws_size,
                              hipStream_t stream) {
    const float* x  = (const float*)d_in[0];
    const float* Wp = (const float*)d_in[1];
    const float* bp = (const float*)d_in[2];
    float* out = (float*)d_out;
    unsigned short* Wb = (unsigned short*)d_ws;   // PREDCH*16 bf16 = 330 KB
    (void)in_sizes; (void)n_in; (void)out_size; (void)ws_size;

    hipLaunchKernelGGL(cvt_wp, dim3(160), dim3(256), 0, stream, Wp, Wb);
    hipLaunchKernelGGL(dppc16, dim3(BATCH * 128), dim3(1024), 0, stream, x, Wb, bp, out);
}

// Round 10
// 121.361 us; speedup vs baseline: 1.0642x; 1.0642x over previous
//
#include <hip/hip_runtime.h>
#include <math.h>

#define CIN    64
#define OUTC   64
#define BOT    16
#define KK     9
#define HH     48
#define WW     48
#define LPIX   (HH*WW)
#define WSZ    9216
#define PSZ    1024
#define PREDCH 10304
#define GRPSZ  2576
#define BATCH  2
#define NPX    18          // 3 rows x 6 cols of pixels per block
#define PXS2   1172        // px-stride (ushorts): 64*18 + 20 pad (conflict-free)
#define QS2    1160        // Q px-stride (ushorts): 64*18 + 8 pad
#define DBS    65

typedef __attribute__((ext_vector_type(8))) short short8v;
typedef __attribute__((ext_vector_type(4))) float float4v;

__device__ inline unsigned short f2bf(float f){
    unsigned u = __float_as_uint(f);
    return (unsigned short)((u + 0x7FFFu + ((u>>16)&1u)) >> 16);   // RNE
}

__global__ __launch_bounds__(256) void cvt_wp(const float* __restrict__ Wp,
                                              unsigned short* __restrict__ Wb) {
    const int n = PREDCH * 16;
    for (int i = blockIdx.x * 256 + threadIdx.x; i < n; i += gridDim.x * 256)
        Wb[i] = f2bf(Wp[i]);
}

// Block = 18 px (3x6), grid 256 (1/CU), 1024 threads (16 waves).
// vs dppc16 (R9, 77.0us REGRESSION): R9 bundled {3/5 PRED split, rsqrt}.
// The split was wrong in SIGN: a PRED u-iter costs ~1.5x a Y-task (Wb
// global load + ~1.7 straddled MFMAs + stores vs LDS-local Y), so R8's
// crit path 4P+5Y=11 became 5P+4Y=11.5 on waves 8-15 (+3% measured).
// This round decouples: revert to R8's uniform 4P split, KEEP rsqrt
// (R9 showed it cuts VALU issue: VALUBusy 61->54.5; its gain was masked
// by the worse straggler).  Everything else R8-verbatim.
__global__ __launch_bounds__(1024) __attribute__((amdgpu_waves_per_eu(4, 4)))
void dppc17(
    const float* __restrict__ x,
    const unsigned short* __restrict__ Wb,
    const float* __restrict__ bp,
    float* __restrict__ out)
{
    __shared__ float          xt[64 * 5 * 8];       // 10240 B  [c][r5][c8]
    __shared__ float          xtT[5 * 8 * 64];      // 10240 B  [r5*8+c8][c]
    __shared__ unsigned short S[2][NPX * PXS2];     // 84384 B  P_t dbuf
    __shared__ unsigned short Qs[NPX * QS2];        // 41760 B  Q [px][o*18+d]
    __shared__ unsigned short Bfs[4 * 2 * 64 * 8];  //  8192 B  pred B-frags [g][nt][lane]
    __shared__ float          dynb[NPX * DBS];      //  4680 B

    const int tid  = threadIdx.x;
    const int wave = tid >> 6;
    const int lane = tid & 63;
    const int quad = lane >> 4;
    const int lrow = lane & 15;

    const int bi = blockIdx.x;
    const int b  = bi >> 7;
    const int r  = bi & 127;
    const int h0 = (r >> 3) * 3;
    const int w0 = (r & 7) * 6;

    // ---- xt load (coalesced global) ----
    const float* xb = x + (size_t)b * CIN * LPIX;
    for (int i = tid; i < 64 * 5 * 8; i += 1024) {
        const int c  = i / 40;
        const int rm = i - c * 40;
        const int hi = h0 - 1 + (rm >> 3);
        const int wi = w0 - 1 + (rm & 7);
        float v = 0.0f;
        if (hi >= 0 && hi < HH && wi >= 0 && wi < WW)
            v = xb[c * LPIX + hi * WW + wi];
        xt[i] = v;
    }
    __syncthreads();

    // ---- waves 0-7: pred B-frags -> LDS (wave-invariant, built once) ----
    if (wave < 8) {
        const int g  = wave >> 1;
        const int nt = wave & 1;
        const int px = nt * 16 + lrow;
        short8v f = (short8v)0;
        if (quad < 2 && px < NPX) {
            const int pr = px / 6, pc = px - 6 * (px / 6);
            #pragma unroll
            for (int j = 0; j < 8; ++j)
                f[j] = (short)f2bf(xt[((g * 16 + quad * 8 + j) * 5 + pr + 1) * 8 + pc + 1]);
        }
        if (quad == 2 && px < NPX) f[0] = (short)0x3F80;   // bf16(1.0) bias slot
        *(short8v*)&Bfs[((g * 2 + nt) * 64 + lane) * 8] = f;
    } else {
        // ---- waves 8-15: transpose xt -> xtT[spatial][c] (for pv b128 reads) ----
        for (int i = tid - 512; i < 64 * 5 * 8; i += 512) {
            const int sp = i >> 6;
            const int c  = i & 63;
            xtT[i] = xt[c * 40 + sp];
        }
    }
    __syncthreads();

    // ---- Q + dyn_b phase (group 3), Q -> Qs as [px][o*18+d] ----
    for (int u = wave; u < 68; u += 16) {
        const int ch0  = WSZ + u * 16;
        const int mych = ch0 + lrow;
        short8v a = (short8v)0;
        if (quad < 2)       a = *(const short8v*)(Wb + (size_t)mych * 16 + quad * 8);
        else if (quad == 2) a[0] = (short)f2bf(bp[mych]);
        #pragma unroll
        for (int nt = 0; nt < 2; ++nt) {
            const short8v bfr = *(const short8v*)&Bfs[((3 * 2 + nt) * 64 + lane) * 8];
            float4v Dv = {0.f, 0.f, 0.f, 0.f};
            Dv = __builtin_amdgcn_mfma_f32_16x16x32_bf16(a, bfr, Dv, 0, 0, 0);
            const int px = nt * 16 + lrow;
            if (px < NPX) {
                if (u < 64) {   // proj region: 4 consecutive ushorts, C-packed b32
                    const unsigned r01 = (unsigned)f2bf(Dv[0]) | ((unsigned)f2bf(Dv[1]) << 16);
                    const unsigned r23 = (unsigned)f2bf(Dv[2]) | ((unsigned)f2bf(Dv[3]) << 16);
                    unsigned short* p = &Qs[px * QS2 + u * 18 + quad * 4];
                    *(unsigned int*)(p)     = r01;
                    *(unsigned int*)(p + 2) = r23;
                } else {        // dyn_b region
                    #pragma unroll
                    for (int rr = 0; rr < 4; ++rr)
                        dynb[px * DBS + (u - 64) * 16 + quad * 4 + rr] = Dv[rr];
                }
            }
        }
    }

    // ---- pred slice for tap t into buf ----
    // Row remap: A-row lrow -> channel chmin + (lrow&3)*576 + (lrow>>2)*9,
    // so Dv[rr] = (d=d0+rr, c=c0+quad): d-consecutive -> C-packed b32 stores.
    #define PASS(GG, NT)                                                              \
        { short8v am = (myg == (GG)) ? a : (short8v)0;                                \
          const short8v bfr = *(const short8v*)&Bfs[(((GG) * 2 + (NT)) * 64 + lane) * 8]; \
          Dv = __builtin_amdgcn_mfma_f32_16x16x32_bf16(am, bfr, Dv, 0, 0, 0); }

    #define PRED_SLICE(T, BUF)                                                        \
    for (int u = wave; u < 64; u += 16) {                                             \
        const int d0 = (u >> 4) * 4;                                                  \
        const int c0 = (u & 15) * 4;                                                  \
        const int chmin = d0 * 576 + c0 * 9 + (T);                                    \
        const int mych  = chmin + (lrow & 3) * 576 + (lrow >> 2) * 9;                 \
        short8v a = (short8v)0;                                                       \
        if (quad < 2)       a = *(const short8v*)(Wb + (size_t)mych * 16 + quad * 8); \
        else if (quad == 2) a[0] = (short)f2bf(bp[mych]);                             \
        const int g0  = chmin / GRPSZ;                                                \
        const int g1  = (chmin + 1755) / GRPSZ;                                       \
        const int myg = mych / GRPSZ;                                                 \
        _Pragma("unroll")                                                             \
        for (int nt = 0; nt < 2; ++nt) {                                              \
            float4v Dv = {0.f, 0.f, 0.f, 0.f};                                        \
            if (g0 == 0)      { PASS(0, nt) if (g1 == 1) PASS(1, nt) }                \
            else if (g0 == 1) { PASS(1, nt) if (g1 == 2) PASS(2, nt) }                \
            else if (g0 == 2) { PASS(2, nt) if (g1 == 3) PASS(3, nt) }                \
            else              { PASS(3, nt) }                                         \
            const int px = nt * 16 + lrow;                                            \
            if (px < NPX) {                                                           \
                const unsigned r01 = (unsigned)f2bf(Dv[0]) | ((unsigned)f2bf(Dv[1]) << 16); \
                const unsigned r23 = (unsigned)f2bf(Dv[2]) | ((unsigned)f2bf(Dv[3]) << 16); \
                unsigned short* p = &S[BUF][px * PXS2 + (c0 + quad) * 18 + d0];       \
                *(unsigned int*)(p)     = r01;                                        \
                *(unsigned int*)(p + 2) = r23;                                        \
            }                                                                         \
        }                                                                             \
    }

    PRED_SLICE(0, 0)
    __syncthreads();   // covers Qs, dynb, S[0]

    // ---- Y-task assignment: 72 (px,Nt) tasks over 16 waves ----
    const int ntask  = (wave < 8) ? 5 : 4;
    const int tstart = (wave < 8) ? 5 * wave : 40 + 4 * (wave - 8);
    float acc[5] = {0.f, 0.f, 0.f, 0.f, 0.f};

    for (int t = 0; t < KK; ++t) {
        const int buf = t & 1;
        if (t < 8) { PRED_SLICE(t + 1, (t + 1) & 1) }

        const int tr = t / 3, tc = t - 3 * (t / 3);

        int lastpx = -1;
        short8v Ap[4];
        float4v pv4[4];
        #pragma unroll
        for (int k = 0; k < 5; ++k) {
            if (k < ntask) {
                const int tau = tstart + k;
                const int px  = tau >> 2;
                const int Nt  = tau & 3;
                const int pr = px / 6, pc = px - 6 * (px / 6);

                if (px != lastpx) {          // wave-uniform branch
                    lastpx = px;
                    #pragma unroll
                    for (int Mt = 0; Mt < 4; ++Mt) {
                        short8v f = (short8v)0;
                        if (quad < 2)
                            f = *(const short8v*)&S[buf][px * PXS2 + (Mt * 16 + lrow) * 18 + quad * 8];
                        Ap[Mt] = f;
                    }
                    const int spb = ((pr + tr) * 8 + pc + tc) * 64;
                    #pragma unroll
                    for (int Mt = 0; Mt < 4; ++Mt)
                        pv4[Mt] = *(const float4v*)&xtT[spb + Mt * 16 + quad * 4];
                }

                short8v Bqf = (short8v)0;
                if (quad < 2)
                    Bqf = *(const short8v*)&Qs[px * QS2 + (Nt * 16 + lrow) * 18 + quad * 8];

                float nacc = 0.f, dpacc = 0.f;
                #pragma unroll
                for (int Mt = 0; Mt < 4; ++Mt) {
                    float4v Dv = {0.f, 0.f, 0.f, 0.f};
                    Dv = __builtin_amdgcn_mfma_f32_16x16x32_bf16(Ap[Mt], Bqf, Dv, 0, 0, 0);
                    #pragma unroll
                    for (int rr = 0; rr < 4; ++rr) {
                        nacc  += Dv[rr] * Dv[rr];
                        dpacc += pv4[Mt][rr] * Dv[rr];
                    }
                }
                nacc  += __shfl_xor(nacc, 16);  nacc  += __shfl_xor(nacc, 32);
                dpacc += __shfl_xor(dpacc, 16); dpacc += __shfl_xor(dpacc, 32);
                acc[k] += dpacc * rsqrtf(fmaxf(nacc, 1e-24f));
            }
        }
        __syncthreads();
    }

    // ---- write out ----
    if (quad == 0) {
        #pragma unroll
        for (int k = 0; k < 5; ++k) {
            if (k < ntask) {
                const int tau = tstart + k;
                const int px  = tau >> 2;
                const int Nt  = tau & 3;
                const int pr = px / 6, pc = px - 6 * (px / 6);
                const int l  = (h0 + pr) * WW + (w0 + pc);
                const int o  = Nt * 16 + lrow;
                out[((size_t)b * OUTC + o) * LPIX + l] = acc[k] + dynb[px * DBS + o];
            }
        }
    }
}

extern "C" void kernel_launch(void* const* d_in, const int* in_sizes, int n_in,
                              void* d_out, int out_size, void* d_ws, size_t ws_size,
                              hipStream_t stream) {
    const float* x  = (const float*)d_in[0];
    const float* Wp = (const float*)d_in[1];
    const float* bp = (const float*)d_in[2];
    float* out = (float*)d_out;
    unsigned short* Wb = (unsigned short*)d_ws;   // PREDCH*16 bf16 = 330 KB
    (void)in_sizes; (void)n_in; (void)out_size; (void)ws_size;

    hipLaunchKernelGGL(cvt_wp, dim3(160), dim3(256), 0, stream, Wp, Wb);
    hipLaunchKernelGGL(dppc17, dim3(BATCH * 128), dim3(1024), 0, stream, x, Wb, bp, out);
}

// Round 11
// 116.211 us; speedup vs baseline: 1.1113x; 1.0443x over previous
//
#include <hip/hip_runtime.h>
#include <math.h>

#define CIN    64
#define OUTC   64
#define BOT    16
#define KK     9
#define HH     48
#define WW     48
#define LPIX   (HH*WW)
#define WSZ    9216
#define PSZ    1024
#define PREDCH 10304
#define GRPSZ  2576
#define BATCH  2
#define NPX    18          // 3 rows x 6 cols of pixels per block
#define PXS2   1172        // px-stride (ushorts): 64*18 + 20 pad (conflict-free)
#define QS2    1160        // Q px-stride (ushorts): 64*18 + 8 pad
#define DBS    65

typedef __attribute__((ext_vector_type(8))) short short8v;
typedef __attribute__((ext_vector_type(4))) float float4v;

__device__ inline unsigned short f2bf(float f){
    unsigned u = __float_as_uint(f);
    return (unsigned short)((u + 0x7FFFu + ((u>>16)&1u)) >> 16);   // RNE
}

__global__ __launch_bounds__(256) void cvt_wp(const float* __restrict__ Wp,
                                              unsigned short* __restrict__ Wb) {
    const int n = PREDCH * 16;
    for (int i = blockIdx.x * 256 + threadIdx.x; i < n; i += gridDim.x * 256)
        Wb[i] = f2bf(Wp[i]);
}

// Block = 18 px (3x6), grid 256 (1/CU), 1024 threads (16 waves).
// vs dppc17 (R10, 70.0us): cross-tap PREFETCH of the PRED A-fragments.
// Each tap's PRED issued 4 dependent Wb global loads (L2-resident, ~200cy)
// in barrier-locked phase across all 16 waves -> TLP can't cover the stall
// (all waves stall on the same pattern).  Now apre[4] (16 VGPRs) is built
// one tap EARLY: loop = COMPUTE(t+1) from apre -> PREFETCH(t+2) -> Y(t) ->
// barrier, so the loads get a full Y-phase + barrier (~1000s cy) to land.
// Fully-unrolled static apre indexing (no scratch).  Single mechanism;
// everything else R10-verbatim.
__global__ __launch_bounds__(1024) __attribute__((amdgpu_waves_per_eu(4, 4)))
void dppc18(
    const float* __restrict__ x,
    const unsigned short* __restrict__ Wb,
    const float* __restrict__ bp,
    float* __restrict__ out)
{
    __shared__ float          xt[64 * 5 * 8];       // 10240 B  [c][r5][c8]
    __shared__ float          xtT[5 * 8 * 64];      // 10240 B  [r5*8+c8][c]
    __shared__ unsigned short S[2][NPX * PXS2];     // 84384 B  P_t dbuf
    __shared__ unsigned short Qs[NPX * QS2];        // 41760 B  Q [px][o*18+d]
    __shared__ unsigned short Bfs[4 * 2 * 64 * 8];  //  8192 B  pred B-frags [g][nt][lane]
    __shared__ float          dynb[NPX * DBS];      //  4680 B

    const int tid  = threadIdx.x;
    const int wave = tid >> 6;
    const int lane = tid & 63;
    const int quad = lane >> 4;
    const int lrow = lane & 15;

    const int bi = blockIdx.x;
    const int b  = bi >> 7;
    const int r  = bi & 127;
    const int h0 = (r >> 3) * 3;
    const int w0 = (r & 7) * 6;

    // ---- xt load (coalesced global) ----
    const float* xb = x + (size_t)b * CIN * LPIX;
    for (int i = tid; i < 64 * 5 * 8; i += 1024) {
        const int c  = i / 40;
        const int rm = i - c * 40;
        const int hi = h0 - 1 + (rm >> 3);
        const int wi = w0 - 1 + (rm & 7);
        float v = 0.0f;
        if (hi >= 0 && hi < HH && wi >= 0 && wi < WW)
            v = xb[c * LPIX + hi * WW + wi];
        xt[i] = v;
    }
    __syncthreads();

    // ---- waves 0-7: pred B-frags -> LDS (wave-invariant, built once) ----
    if (wave < 8) {
        const int g  = wave >> 1;
        const int nt = wave & 1;
        const int px = nt * 16 + lrow;
        short8v f = (short8v)0;
        if (quad < 2 && px < NPX) {
            const int pr = px / 6, pc = px - 6 * (px / 6);
            #pragma unroll
            for (int j = 0; j < 8; ++j)
                f[j] = (short)f2bf(xt[((g * 16 + quad * 8 + j) * 5 + pr + 1) * 8 + pc + 1]);
        }
        if (quad == 2 && px < NPX) f[0] = (short)0x3F80;   // bf16(1.0) bias slot
        *(short8v*)&Bfs[((g * 2 + nt) * 64 + lane) * 8] = f;
    } else {
        // ---- waves 8-15: transpose xt -> xtT[spatial][c] (for pv b128 reads) ----
        for (int i = tid - 512; i < 64 * 5 * 8; i += 512) {
            const int sp = i >> 6;
            const int c  = i & 63;
            xtT[i] = xt[c * 40 + sp];
        }
    }
    __syncthreads();

    // ---- Q + dyn_b phase (group 3), Q -> Qs as [px][o*18+d] ----
    for (int u = wave; u < 68; u += 16) {
        const int ch0  = WSZ + u * 16;
        const int mych = ch0 + lrow;
        short8v a = (short8v)0;
        if (quad < 2)       a = *(const short8v*)(Wb + (size_t)mych * 16 + quad * 8);
        else if (quad == 2) a[0] = (short)f2bf(bp[mych]);
        #pragma unroll
        for (int nt = 0; nt < 2; ++nt) {
            const short8v bfr = *(const short8v*)&Bfs[((3 * 2 + nt) * 64 + lane) * 8];
            float4v Dv = {0.f, 0.f, 0.f, 0.f};
            Dv = __builtin_amdgcn_mfma_f32_16x16x32_bf16(a, bfr, Dv, 0, 0, 0);
            const int px = nt * 16 + lrow;
            if (px < NPX) {
                if (u < 64) {   // proj region: 4 consecutive ushorts, C-packed b32
                    const unsigned r01 = (unsigned)f2bf(Dv[0]) | ((unsigned)f2bf(Dv[1]) << 16);
                    const unsigned r23 = (unsigned)f2bf(Dv[2]) | ((unsigned)f2bf(Dv[3]) << 16);
                    unsigned short* p = &Qs[px * QS2 + u * 18 + quad * 4];
                    *(unsigned int*)(p)     = r01;
                    *(unsigned int*)(p + 2) = r23;
                } else {        // dyn_b region
                    #pragma unroll
                    for (int rr = 0; rr < 4; ++rr)
                        dynb[px * DBS + (u - 64) * 16 + quad * 4 + rr] = Dv[rr];
                }
            }
        }
    }

    // ---- cross-tap A-fragment prefetch registers (static indexing only) ----
    short8v apre[4];

    #define PRED_PREFETCH(T)                                                          \
    _Pragma("unroll")                                                                 \
    for (int uu = 0; uu < 4; ++uu) {                                                  \
        const int u  = wave + uu * 16;                                                \
        const int d0 = (u >> 4) * 4;                                                  \
        const int c0 = (u & 15) * 4;                                                  \
        const int chmin = d0 * 576 + c0 * 9 + (T);                                    \
        const int mych  = chmin + (lrow & 3) * 576 + (lrow >> 2) * 9;                 \
        short8v a = (short8v)0;                                                       \
        if (quad < 2)       a = *(const short8v*)(Wb + (size_t)mych * 16 + quad * 8); \
        else if (quad == 2) a[0] = (short)f2bf(bp[mych]);                             \
        apre[uu] = a;                                                                 \
    }

    // ---- pred slice for tap t into buf ----
    // Row remap: A-row lrow -> channel chmin + (lrow&3)*576 + (lrow>>2)*9,
    // so Dv[rr] = (d=d0+rr, c=c0+quad): d-consecutive -> C-packed b32 stores.
    #define PASS(GG, NT)                                                              \
        { short8v am = (myg == (GG)) ? a : (short8v)0;                                \
          const short8v bfr = *(const short8v*)&Bfs[(((GG) * 2 + (NT)) * 64 + lane) * 8]; \
          Dv = __builtin_amdgcn_mfma_f32_16x16x32_bf16(am, bfr, Dv, 0, 0, 0); }

    // BODY: shared tail of PRED (group select + MFMA + packed store); `a` in scope.
    #define PRED_BODY(T, BUF)                                                         \
        const int g0  = chmin / GRPSZ;                                                \
        const int g1  = (chmin + 1755) / GRPSZ;                                       \
        const int myg = mych / GRPSZ;                                                 \
        _Pragma("unroll")                                                             \
        for (int nt = 0; nt < 2; ++nt) {                                              \
            float4v Dv = {0.f, 0.f, 0.f, 0.f};                                        \
            if (g0 == 0)      { PASS(0, nt) if (g1 == 1) PASS(1, nt) }                \
            else if (g0 == 1) { PASS(1, nt) if (g1 == 2) PASS(2, nt) }                \
            else if (g0 == 2) { PASS(2, nt) if (g1 == 3) PASS(3, nt) }                \
            else              { PASS(3, nt) }                                         \
            const int px = nt * 16 + lrow;                                            \
            if (px < NPX) {                                                           \
                const unsigned r01 = (unsigned)f2bf(Dv[0]) | ((unsigned)f2bf(Dv[1]) << 16); \
                const unsigned r23 = (unsigned)f2bf(Dv[2]) | ((unsigned)f2bf(Dv[3]) << 16); \
                unsigned short* p = &S[BUF][px * PXS2 + (c0 + quad) * 18 + d0];       \
                *(unsigned int*)(p)     = r01;                                        \
                *(unsigned int*)(p + 2) = r23;                                        \
            }                                                                         \
        }

    // tap-0 PRED: inline loads (prologue, nothing to prefetch from)
    #define PRED_SLICE0(T, BUF)                                                       \
    for (int u = wave; u < 64; u += 16) {                                             \
        const int d0 = (u >> 4) * 4;                                                  \
        const int c0 = (u & 15) * 4;                                                  \
        const int chmin = d0 * 576 + c0 * 9 + (T);                                    \
        const int mych  = chmin + (lrow & 3) * 576 + (lrow >> 2) * 9;                 \
        short8v a = (short8v)0;                                                       \
        if (quad < 2)       a = *(const short8v*)(Wb + (size_t)mych * 16 + quad * 8); \
        else if (quad == 2) a[0] = (short)f2bf(bp[mych]);                             \
        PRED_BODY(T, BUF)                                                             \
    }

    // steady-state PRED: consumes apre (prefetched one tap earlier)
    #define PRED_COMPUTE(T, BUF)                                                      \
    _Pragma("unroll")                                                                 \
    for (int uu = 0; uu < 4; ++uu) {                                                  \
        const int u  = wave + uu * 16;                                                \
        const int d0 = (u >> 4) * 4;                                                  \
        const int c0 = (u & 15) * 4;                                                  \
        const int chmin = d0 * 576 + c0 * 9 + (T);                                    \
        const int mych  = chmin + (lrow & 3) * 576 + (lrow >> 2) * 9;                 \
        short8v a = apre[uu];                                                         \
        PRED_BODY(T, BUF)                                                             \
    }

    PRED_SLICE0(0, 0)
    PRED_PREFETCH(1)
    __syncthreads();   // covers Qs, dynb, S[0]

    // ---- Y-task assignment: 72 (px,Nt) tasks over 16 waves ----
    const int ntask  = (wave < 8) ? 5 : 4;
    const int tstart = (wave < 8) ? 5 * wave : 40 + 4 * (wave - 8);
    float acc[5] = {0.f, 0.f, 0.f, 0.f, 0.f};

    for (int t = 0; t < KK; ++t) {
        const int buf = t & 1;
        if (t < 8) { PRED_COMPUTE(t + 1, (t + 1) & 1) }
        if (t < 7) { PRED_PREFETCH(t + 2) }

        const int tr = t / 3, tc = t - 3 * (t / 3);

        int lastpx = -1;
        short8v Ap[4];
        float4v pv4[4];
        #pragma unroll
        for (int k = 0; k < 5; ++k) {
            if (k < ntask) {
                const int tau = tstart + k;
                const int px  = tau >> 2;
                const int Nt  = tau & 3;
                const int pr = px / 6, pc = px - 6 * (px / 6);

                if (px != lastpx) {          // wave-uniform branch
                    lastpx = px;
                    #pragma unroll
                    for (int Mt = 0; Mt < 4; ++Mt) {
                        short8v f = (short8v)0;
                        if (quad < 2)
                            f = *(const short8v*)&S[buf][px * PXS2 + (Mt * 16 + lrow) * 18 + quad * 8];
                        Ap[Mt] = f;
                    }
                    const int spb = ((pr + tr) * 8 + pc + tc) * 64;
                    #pragma unroll
                    for (int Mt = 0; Mt < 4; ++Mt)
                        pv4[Mt] = *(const float4v*)&xtT[spb + Mt * 16 + quad * 4];
                }

                short8v Bqf = (short8v)0;
                if (quad < 2)
                    Bqf = *(const short8v*)&Qs[px * QS2 + (Nt * 16 + lrow) * 18 + quad * 8];

                float nacc = 0.f, dpacc = 0.f;
                #pragma unroll
                for (int Mt = 0; Mt < 4; ++Mt) {
                    float4v Dv = {0.f, 0.f, 0.f, 0.f};
                    Dv = __builtin_amdgcn_mfma_f32_16x16x32_bf16(Ap[Mt], Bqf, Dv, 0, 0, 0);
                    #pragma unroll
                    for (int rr = 0; rr < 4; ++rr) {
                        nacc  += Dv[rr] * Dv[rr];
                        dpacc += pv4[Mt][rr] * Dv[rr];
                    }
                }
                nacc  += __shfl_xor(nacc, 16);  nacc  += __shfl_xor(nacc, 32);
                dpacc += __shfl_xor(dpacc, 16); dpacc += __shfl_xor(dpacc, 32);
                acc[k] += dpacc * rsqrtf(fmaxf(nacc, 1e-24f));
            }
        }
        __syncthreads();
    }

    // ---- write out ----
    if (quad == 0) {
        #pragma unroll
        for (int k = 0; k < 5; ++k) {
            if (k < ntask) {
                const int tau = tstart + k;
                const int px  = tau >> 2;
                const int Nt  = tau & 3;
                const int pr = px / 6, pc = px - 6 * (px / 6);
                const int l  = (h0 + pr) * WW + (w0 + pc);
                const int o  = Nt * 16 + lrow;
                out[((size_t)b * OUTC + o) * LPIX + l] = acc[k] + dynb[px * DBS + o];
            }
        }
    }
}

extern "C" void kernel_launch(void* const* d_in, const int* in_sizes, int n_in,
                              void* d_out, int out_size, void* d_ws, size_t ws_size,
                              hipStream_t stream) {
    const float* x  = (const float*)d_in[0];
    const float* Wp = (const float*)d_in[1];
    const float* bp = (const float*)d_in[2];
    float* out = (float*)d_out;
    unsigned short* Wb = (unsigned short*)d_ws;   // PREDCH*16 bf16 = 330 KB
    (void)in_sizes; (void)n_in; (void)out_size; (void)ws_size;

    hipLaunchKernelGGL(cvt_wp, dim3(160), dim3(256), 0, stream, Wp, Wb);
    hipLaunchKernelGGL(dppc18, dim3(BATCH * 128), dim3(1024), 0, stream, x, Wb, bp, out);
}

// Round 12
// 115.562 us; speedup vs baseline: 1.1176x; 1.0056x over previous
//
#include <hip/hip_runtime.h>
#include <math.h>

#define CIN    64
#define OUTC   64
#define BOT    16
#define KK     9
#define HH     48
#define WW     48
#define LPIX   (HH*WW)
#define WSZ    9216
#define PSZ    1024
#define PREDCH 10304
#define GRPSZ  2576
#define BATCH  2
#define NPX    18          // 3 rows x 6 cols of pixels per block
#define PXS2   1172        // px-stride (ushorts): 64*18 + 20 pad (conflict-free)
#define QS2    1160        // Q px-stride (ushorts): 64*18 + 8 pad
#define DBS    65

typedef __attribute__((ext_vector_type(8))) short short8v;
typedef __attribute__((ext_vector_type(4))) float float4v;

__device__ inline unsigned short f2bf(float f){
    unsigned u = __float_as_uint(f);
    return (unsigned short)((u + 0x7FFFu + ((u>>16)&1u)) >> 16);   // RNE
}

__global__ __launch_bounds__(256) void cvt_wp(const float* __restrict__ Wp,
                                              unsigned short* __restrict__ Wb) {
    const int n = PREDCH * 16;
    for (int i = blockIdx.x * 256 + threadIdx.x; i < n; i += gridDim.x * 256)
        Wb[i] = f2bf(Wp[i]);
}

// Block = 18 px (3x6), grid 256 (1/CU), 1024 threads (16 waves).
// vs dppc18 (R11): apre[4] (16 VGPRs) pushed Y-phase live state to 72, over
// the hard 64-VGPR allocator ceiling (R3/R4/R11: it stays at 64 and SPILLS
// rather than grow; launch_bounds/waves_per_eu can't raise it) -> 11 MB
// scratch ate ~half the prefetch gain (profiled 73.6 vs wall-implied ~65).
// R10 was 56 VGPRs -> exactly 8 spare.  So: apre[2] (8 VGPRs) -- prefetch
// u-iters 0-1 across the Y-phase, inline-load u-iters 2-3 at compute time
// (their stall partially covered by iters 0-1's MFMAs already in flight).
// Half the hiding, zero spill.  Single knob vs R11.
__global__ __launch_bounds__(1024) __attribute__((amdgpu_waves_per_eu(4, 4)))
void dppc19(
    const float* __restrict__ x,
    const unsigned short* __restrict__ Wb,
    const float* __restrict__ bp,
    float* __restrict__ out)
{
    __shared__ float          xt[64 * 5 * 8];       // 10240 B  [c][r5][c8]
    __shared__ float          xtT[5 * 8 * 64];      // 10240 B  [r5*8+c8][c]
    __shared__ unsigned short S[2][NPX * PXS2];     // 84384 B  P_t dbuf
    __shared__ unsigned short Qs[NPX * QS2];        // 41760 B  Q [px][o*18+d]
    __shared__ unsigned short Bfs[4 * 2 * 64 * 8];  //  8192 B  pred B-frags [g][nt][lane]
    __shared__ float          dynb[NPX * DBS];      //  4680 B

    const int tid  = threadIdx.x;
    const int wave = tid >> 6;
    const int lane = tid & 63;
    const int quad = lane >> 4;
    const int lrow = lane & 15;

    const int bi = blockIdx.x;
    const int b  = bi >> 7;
    const int r  = bi & 127;
    const int h0 = (r >> 3) * 3;
    const int w0 = (r & 7) * 6;

    // ---- xt load (coalesced global) ----
    const float* xb = x + (size_t)b * CIN * LPIX;
    for (int i = tid; i < 64 * 5 * 8; i += 1024) {
        const int c  = i / 40;
        const int rm = i - c * 40;
        const int hi = h0 - 1 + (rm >> 3);
        const int wi = w0 - 1 + (rm & 7);
        float v = 0.0f;
        if (hi >= 0 && hi < HH && wi >= 0 && wi < WW)
            v = xb[c * LPIX + hi * WW + wi];
        xt[i] = v;
    }
    __syncthreads();

    // ---- waves 0-7: pred B-frags -> LDS (wave-invariant, built once) ----
    if (wave < 8) {
        const int g  = wave >> 1;
        const int nt = wave & 1;
        const int px = nt * 16 + lrow;
        short8v f = (short8v)0;
        if (quad < 2 && px < NPX) {
            const int pr = px / 6, pc = px - 6 * (px / 6);
            #pragma unroll
            for (int j = 0; j < 8; ++j)
                f[j] = (short)f2bf(xt[((g * 16 + quad * 8 + j) * 5 + pr + 1) * 8 + pc + 1]);
        }
        if (quad == 2 && px < NPX) f[0] = (short)0x3F80;   // bf16(1.0) bias slot
        *(short8v*)&Bfs[((g * 2 + nt) * 64 + lane) * 8] = f;
    } else {
        // ---- waves 8-15: transpose xt -> xtT[spatial][c] (for pv b128 reads) ----
        for (int i = tid - 512; i < 64 * 5 * 8; i += 512) {
            const int sp = i >> 6;
            const int c  = i & 63;
            xtT[i] = xt[c * 40 + sp];
        }
    }
    __syncthreads();

    // ---- Q + dyn_b phase (group 3), Q -> Qs as [px][o*18+d] ----
    for (int u = wave; u < 68; u += 16) {
        const int ch0  = WSZ + u * 16;
        const int mych = ch0 + lrow;
        short8v a = (short8v)0;
        if (quad < 2)       a = *(const short8v*)(Wb + (size_t)mych * 16 + quad * 8);
        else if (quad == 2) a[0] = (short)f2bf(bp[mych]);
        #pragma unroll
        for (int nt = 0; nt < 2; ++nt) {
            const short8v bfr = *(const short8v*)&Bfs[((3 * 2 + nt) * 64 + lane) * 8];
            float4v Dv = {0.f, 0.f, 0.f, 0.f};
            Dv = __builtin_amdgcn_mfma_f32_16x16x32_bf16(a, bfr, Dv, 0, 0, 0);
            const int px = nt * 16 + lrow;
            if (px < NPX) {
                if (u < 64) {   // proj region: 4 consecutive ushorts, C-packed b32
                    const unsigned r01 = (unsigned)f2bf(Dv[0]) | ((unsigned)f2bf(Dv[1]) << 16);
                    const unsigned r23 = (unsigned)f2bf(Dv[2]) | ((unsigned)f2bf(Dv[3]) << 16);
                    unsigned short* p = &Qs[px * QS2 + u * 18 + quad * 4];
                    *(unsigned int*)(p)     = r01;
                    *(unsigned int*)(p + 2) = r23;
                } else {        // dyn_b region
                    #pragma unroll
                    for (int rr = 0; rr < 4; ++rr)
                        dynb[px * DBS + (u - 64) * 16 + quad * 4 + rr] = Dv[rr];
                }
            }
        }
    }

    // ---- cross-tap A-fragment prefetch: HALF depth (8 VGPRs, fits the 64 cap) ----
    short8v apre[2];

    #define PRED_PREFETCH(T)                                                          \
    _Pragma("unroll")                                                                 \
    for (int uu = 0; uu < 2; ++uu) {                                                  \
        const int u  = wave + uu * 16;                                                \
        const int d0 = (u >> 4) * 4;                                                  \
        const int c0 = (u & 15) * 4;                                                  \
        const int chmin = d0 * 576 + c0 * 9 + (T);                                    \
        const int mych  = chmin + (lrow & 3) * 576 + (lrow >> 2) * 9;                 \
        short8v a = (short8v)0;                                                       \
        if (quad < 2)       a = *(const short8v*)(Wb + (size_t)mych * 16 + quad * 8); \
        else if (quad == 2) a[0] = (short)f2bf(bp[mych]);                             \
        apre[uu] = a;                                                                 \
    }

    // ---- pred slice for tap t into buf ----
    // Row remap: A-row lrow -> channel chmin + (lrow&3)*576 + (lrow>>2)*9,
    // so Dv[rr] = (d=d0+rr, c=c0+quad): d-consecutive -> C-packed b32 stores.
    #define PASS(GG, NT)                                                              \
        { short8v am = (myg == (GG)) ? a : (short8v)0;                                \
          const short8v bfr = *(const short8v*)&Bfs[(((GG) * 2 + (NT)) * 64 + lane) * 8]; \
          Dv = __builtin_amdgcn_mfma_f32_16x16x32_bf16(am, bfr, Dv, 0, 0, 0); }

    // BODY: shared tail of PRED (group select + MFMA + packed store); `a` in scope.
    #define PRED_BODY(T, BUF)                                                         \
        const int g0  = chmin / GRPSZ;                                                \
        const int g1  = (chmin + 1755) / GRPSZ;                                       \
        const int myg = mych / GRPSZ;                                                 \
        _Pragma("unroll")                                                             \
        for (int nt = 0; nt < 2; ++nt) {                                              \
            float4v Dv = {0.f, 0.f, 0.f, 0.f};                                        \
            if (g0 == 0)      { PASS(0, nt) if (g1 == 1) PASS(1, nt) }                \
            else if (g0 == 1) { PASS(1, nt) if (g1 == 2) PASS(2, nt) }                \
            else if (g0 == 2) { PASS(2, nt) if (g1 == 3) PASS(3, nt) }                \
            else              { PASS(3, nt) }                                         \
            const int px = nt * 16 + lrow;                                            \
            if (px < NPX) {                                                           \
                const unsigned r01 = (unsigned)f2bf(Dv[0]) | ((unsigned)f2bf(Dv[1]) << 16); \
                const unsigned r23 = (unsigned)f2bf(Dv[2]) | ((unsigned)f2bf(Dv[3]) << 16); \
                unsigned short* p = &S[BUF][px * PXS2 + (c0 + quad) * 18 + d0];       \
                *(unsigned int*)(p)     = r01;                                        \
                *(unsigned int*)(p + 2) = r23;                                        \
            }                                                                         \
        }

    // tap-0 PRED: inline loads (prologue, nothing to prefetch from)
    #define PRED_SLICE0(T, BUF)                                                       \
    for (int u = wave; u < 64; u += 16) {                                             \
        const int d0 = (u >> 4) * 4;                                                  \
        const int c0 = (u & 15) * 4;                                                  \
        const int chmin = d0 * 576 + c0 * 9 + (T);                                    \
        const int mych  = chmin + (lrow & 3) * 576 + (lrow >> 2) * 9;                 \
        short8v a = (short8v)0;                                                       \
        if (quad < 2)       a = *(const short8v*)(Wb + (size_t)mych * 16 + quad * 8); \
        else if (quad == 2) a[0] = (short)f2bf(bp[mych]);                             \
        PRED_BODY(T, BUF)                                                             \
    }

    // steady-state PRED: uu 0-1 consume apre (prefetched one tap earlier);
    // uu 2-3 load inline (stall partially covered by uu 0-1's MFMAs in flight)
    #define PRED_COMPUTE(T, BUF)                                                      \
    _Pragma("unroll")                                                                 \
    for (int uu = 0; uu < 4; ++uu) {                                                  \
        const int u  = wave + uu * 16;                                                \
        const int d0 = (u >> 4) * 4;                                                  \
        const int c0 = (u & 15) * 4;                                                  \
        const int chmin = d0 * 576 + c0 * 9 + (T);                                    \
        const int mych  = chmin + (lrow & 3) * 576 + (lrow >> 2) * 9;                 \
        short8v a;                                                                    \
        if (uu < 2) {                                                                 \
            a = apre[uu];                                                             \
        } else {                                                                      \
            a = (short8v)0;                                                           \
            if (quad < 2)       a = *(const short8v*)(Wb + (size_t)mych * 16 + quad * 8); \
            else if (quad == 2) a[0] = (short)f2bf(bp[mych]);                         \
        }                                                                             \
        PRED_BODY(T, BUF)                                                             \
    }

    PRED_SLICE0(0, 0)
    PRED_PREFETCH(1)
    __syncthreads();   // covers Qs, dynb, S[0]

    // ---- Y-task assignment: 72 (px,Nt) tasks over 16 waves ----
    const int ntask  = (wave < 8) ? 5 : 4;
    const int tstart = (wave < 8) ? 5 * wave : 40 + 4 * (wave - 8);
    float acc[5] = {0.f, 0.f, 0.f, 0.f, 0.f};

    for (int t = 0; t < KK; ++t) {
        const int buf = t & 1;
        if (t < 8) { PRED_COMPUTE(t + 1, (t + 1) & 1) }
        if (t < 7) { PRED_PREFETCH(t + 2) }

        const int tr = t / 3, tc = t - 3 * (t / 3);

        int lastpx = -1;
        short8v Ap[4];
        float4v pv4[4];
        #pragma unroll
        for (int k = 0; k < 5; ++k) {
            if (k < ntask) {
                const int tau = tstart + k;
                const int px  = tau >> 2;
                const int Nt  = tau & 3;
                const int pr = px / 6, pc = px - 6 * (px / 6);

                if (px != lastpx) {          // wave-uniform branch
                    lastpx = px;
                    #pragma unroll
                    for (int Mt = 0; Mt < 4; ++Mt) {
                        short8v f = (short8v)0;
                        if (quad < 2)
                            f = *(const short8v*)&S[buf][px * PXS2 + (Mt * 16 + lrow) * 18 + quad * 8];
                        Ap[Mt] = f;
                    }
                    const int spb = ((pr + tr) * 8 + pc + tc) * 64;
                    #pragma unroll
                    for (int Mt = 0; Mt < 4; ++Mt)
                        pv4[Mt] = *(const float4v*)&xtT[spb + Mt * 16 + quad * 4];
                }

                short8v Bqf = (short8v)0;
                if (quad < 2)
                    Bqf = *(const short8v*)&Qs[px * QS2 + (Nt * 16 + lrow) * 18 + quad * 8];

                float nacc = 0.f, dpacc = 0.f;
                #pragma unroll
                for (int Mt = 0; Mt < 4; ++Mt) {
                    float4v Dv = {0.f, 0.f, 0.f, 0.f};
                    Dv = __builtin_amdgcn_mfma_f32_16x16x32_bf16(Ap[Mt], Bqf, Dv, 0, 0, 0);
                    #pragma unroll
                    for (int rr = 0; rr < 4; ++rr) {
                        nacc  += Dv[rr] * Dv[rr];
                        dpacc += pv4[Mt][rr] * Dv[rr];
                    }
                }
                nacc  += __shfl_xor(nacc, 16);  nacc  += __shfl_xor(nacc, 32);
                dpacc += __shfl_xor(dpacc, 16); dpacc += __shfl_xor(dpacc, 32);
                acc[k] += dpacc * rsqrtf(fmaxf(nacc, 1e-24f));
            }
        }
        __syncthreads();
    }

    // ---- write out ----
    if (quad == 0) {
        #pragma unroll
        for (int k = 0; k < 5; ++k) {
            if (k < ntask) {
                const int tau = tstart + k;
                const int px  = tau >> 2;
                const int Nt  = tau & 3;
                const int pr = px / 6, pc = px - 6 * (px / 6);
                const int l  = (h0 + pr) * WW + (w0 + pc);
                const int o  = Nt * 16 + lrow;
                out[((size_t)b * OUTC + o) * LPIX + l] = acc[k] + dynb[px * DBS + o];
            }
        }
    }
}

extern "C" void kernel_launch(void* const* d_in, const int* in_sizes, int n_in,
                              void* d_out, int out_size, void* d_ws, size_t ws_size,
                              hipStream_t stream) {
    const float* x  = (const float*)d_in[0];
    const float* Wp = (const float*)d_in[1];
    const float* bp = (const float*)d_in[2];
    float* out = (float*)d_out;
    unsigned short* Wb = (unsigned short*)d_ws;   // PREDCH*16 bf16 = 330 KB
    (void)in_sizes; (void)n_in; (void)out_size; (void)ws_size;

    hipLaunchKernelGGL(cvt_wp, dim3(160), dim3(256), 0, stream, Wp, Wb);
    hipLaunchKernelGGL(dppc19, dim3(BATCH * 128), dim3(1024), 0, stream, x, Wb, bp, out);
}